// Round 1
// baseline (879.924 us; speedup 1.0000x reference)
//
#include <hip/hip_runtime.h>

#define BB 16
#define CC 128
#define HH 64
#define WW 64
#define ZD 128
#define NG 8
#define WPB 147456      // weights per sample = 128*128*9
#define PLANE 4096      // 64*64
#define GROUP_N 65536.f // 16 ch * 4096 px per group

// ---------------- hypernet GEMM: w[b][n] = sum_k z[b][k]*hw[k][n] + hb[n] ----
__global__ __launch_bounds__(256)
void hyper_gemm(const float* __restrict__ z, const float* __restrict__ hw,
                const float* __restrict__ hb, float* __restrict__ wout)
{
    __shared__ float zs[BB * ZD];
    const int tid = threadIdx.x;
    for (int i = tid; i < BB * ZD; i += 256) zs[i] = z[i];
    __syncthreads();

    const int n = blockIdx.x * 256 + tid;
    float acc[BB];
#pragma unroll
    for (int b = 0; b < BB; ++b) acc[b] = 0.f;

#pragma unroll 4
    for (int k = 0; k < ZD; ++k) {
        float hv = hw[(size_t)k * WPB + n];
#pragma unroll
        for (int b = 0; b < BB; ++b) acc[b] += zs[b * ZD + k] * hv;
    }
    const float bias = hb[n];
#pragma unroll
    for (int b = 0; b < BB; ++b) wout[(size_t)b * WPB + n] = acc[b] + bias;
}

// ---------------- per-sample 3x3 conv (+fused input GN/ReLU, +output stats) --
// grid: (8 pixel-row-groups, 8 out-ch groups(=GN group), 16 samples), block 256
// thread: 1 col x 2 rows x 16 out-channels
template <bool NORM_IN>
__global__ __launch_bounds__(256)
void conv3x3(const float* __restrict__ in, const float* __restrict__ wt,
             float* __restrict__ out, float* __restrict__ stats_out,
             const float* __restrict__ stats_in,
             const float* __restrict__ gamma, const float* __restrict__ beta)
{
    const int b   = blockIdx.z;
    const int og  = blockIdx.y;       // out-channel group (== GN group)
    const int pg  = blockIdx.x;       // rows pg*8 .. pg*8+7
    const int tid = threadIdx.x;
    const int px  = tid & 63;
    const int pr  = tid >> 6;         // 0..3
    const int y0  = pg * 8 + pr * 2;  // this thread's rows: y0, y0+1

    __shared__ float wtile[16][16][12];  // [oc][ic][tap] taps padded 9->12 (16B align)
    __shared__ float sc[CC], sb[CC];
    __shared__ float red[8];

    if (NORM_IN) {
        if (tid < CC) {
            int g = tid >> 4;
            float sum  = stats_in[(b * NG + g) * 2 + 0];
            float ssq  = stats_in[(b * NG + g) * 2 + 1];
            float mean = sum * (1.f / GROUP_N);
            float var  = ssq * (1.f / GROUP_N) - mean * mean;
            float inv  = rsqrtf(var + 1e-5f);
            float s    = gamma[tid] * inv;
            sc[tid] = s;
            sb[tid] = beta[tid] - mean * s;
        }
    }

    float acc[16][2];
#pragma unroll
    for (int oo = 0; oo < 16; ++oo) { acc[oo][0] = 0.f; acc[oo][1] = 0.f; }

    const float* wbase = wt + (size_t)b * WPB + og * 16 * 1152;
    const float* ibase = in + (size_t)b * CC * PLANE;

    for (int icc = 0; icc < 8; ++icc) {
        __syncthreads();  // protect wtile from previous iteration's readers
        for (int l = tid; l < 2304; l += 256) {
            int oo = l / 144; int r = l - oo * 144; int ii = r / 9; int tap = r - ii * 9;
            wtile[oo][ii][tap] = wbase[oo * 1152 + (icc * 16 + ii) * 9 + tap];
        }
        __syncthreads();

        for (int ii = 0; ii < 16; ++ii) {
            const int ic = icc * 16 + ii;
            const float* ip = ibase + ic * PLANE;
            const float s_ = NORM_IN ? sc[ic] : 0.f;
            const float b_ = NORM_IN ? sb[ic] : 0.f;

            float xr[4][3];  // rows y0-1..y0+2, cols px-1..px+1
#pragma unroll
            for (int ry = 0; ry < 4; ++ry) {
                int yy = y0 - 1 + ry;
                bool yok = (yy >= 0) & (yy < HH);
#pragma unroll
                for (int rx = 0; rx < 3; ++rx) {
                    int xx = px - 1 + rx;
                    bool ok = yok & (xx >= 0) & (xx < WW);
                    float v = ok ? ip[yy * WW + xx] : 0.f;
                    if (NORM_IN) {
                        // norm+relu only in-bounds: zero-pad stays zero
                        if (ok) v = fmaxf(v * s_ + b_, 0.f);
                    }
                    xr[ry][rx] = v;
                }
            }

#pragma unroll
            for (int oo = 0; oo < 16; ++oo) {
                const float* wp = &wtile[oo][ii][0];
                float4 wa  = *(const float4*)wp;        // taps 0..3
                float4 wb_ = *(const float4*)(wp + 4);  // taps 4..7
                float  w8  = wp[8];
                acc[oo][0] += xr[0][0] * wa.x + xr[0][1] * wa.y + xr[0][2] * wa.z
                            + xr[1][0] * wa.w + xr[1][1] * wb_.x + xr[1][2] * wb_.y
                            + xr[2][0] * wb_.z + xr[2][1] * wb_.w + xr[2][2] * w8;
                acc[oo][1] += xr[1][0] * wa.x + xr[1][1] * wa.y + xr[1][2] * wa.z
                            + xr[2][0] * wa.w + xr[2][1] * wb_.x + xr[2][2] * wb_.y
                            + xr[3][0] * wb_.z + xr[3][1] * wb_.w + xr[3][2] * w8;
            }
        }
    }

    // store raw conv output + accumulate group stats (group == this block's og)
    float s1 = 0.f, s2 = 0.f;
#pragma unroll
    for (int oo = 0; oo < 16; ++oo) {
#pragma unroll
        for (int r = 0; r < 2; ++r) {
            float v = acc[oo][r];
            out[(size_t)((b * CC + og * 16 + oo) * HH + (y0 + r)) * WW + px] = v;
            s1 += v; s2 += v * v;
        }
    }
#pragma unroll
    for (int off = 32; off > 0; off >>= 1) {
        s1 += __shfl_down(s1, off, 64);
        s2 += __shfl_down(s2, off, 64);
    }
    const int wave = tid >> 6;
    if ((tid & 63) == 0) { red[wave * 2] = s1; red[wave * 2 + 1] = s2; }
    __syncthreads();
    if (tid == 0) {
        float t1 = red[0] + red[2] + red[4] + red[6];
        float t2 = red[1] + red[3] + red[5] + red[7];
        atomicAdd(&stats_out[(b * NG + og) * 2 + 0], t1);
        atomicAdd(&stats_out[(b * NG + og) * 2 + 1], t2);
    }
}

// ---------------- final: out = relu(GN2(y2) + x), in place over d_out -------
__global__ __launch_bounds__(256)
void gn_add_relu(float* __restrict__ y2, const float* __restrict__ x,
                 const float* __restrict__ stats, const float* __restrict__ gamma,
                 const float* __restrict__ beta)
{
    const int bc = blockIdx.x;  // 0..2047
    const int b = bc >> 7, c = bc & 127;
    const int g = c >> 4;
    float sum  = stats[(b * NG + g) * 2 + 0];
    float ssq  = stats[(b * NG + g) * 2 + 1];
    float mean = sum * (1.f / GROUP_N);
    float var  = ssq * (1.f / GROUP_N) - mean * mean;
    float inv  = rsqrtf(var + 1e-5f);
    float s = gamma[c] * inv;
    float t = beta[c] - mean * s;

    size_t base = (size_t)bc * PLANE;
    float4* yp = (float4*)(y2 + base);
    const float4* xp = (const float4*)(x + base);
    for (int i = threadIdx.x; i < PLANE / 4; i += 256) {
        float4 v = yp[i], xv = xp[i];
        v.x = fmaxf(v.x * s + t + xv.x, 0.f);
        v.y = fmaxf(v.y * s + t + xv.y, 0.f);
        v.z = fmaxf(v.z * s + t + xv.z, 0.f);
        v.w = fmaxf(v.w * s + t + xv.w, 0.f);
        yp[i] = v;
    }
}

extern "C" void kernel_launch(void* const* d_in, const int* in_sizes, int n_in,
                              void* d_out, int out_size, void* d_ws, size_t ws_size,
                              hipStream_t stream)
{
    const float* x   = (const float*)d_in[0];
    const float* z   = (const float*)d_in[1];
    const float* h1w = (const float*)d_in[2];
    const float* h1b = (const float*)d_in[3];
    const float* h2w = (const float*)d_in[4];
    const float* h2b = (const float*)d_in[5];
    const float* g1  = (const float*)d_in[6];
    const float* b1  = (const float*)d_in[7];
    const float* g2  = (const float*)d_in[8];
    const float* b2  = (const float*)d_in[9];
    float* out = (float*)d_out;

    // workspace layout (floats): y1[8388608] | w[2359296] | st1[256] | st2[256]
    float* ws  = (float*)d_ws;
    float* y1  = ws;
    float* wsl = ws + 8388608;           // shared slot for w1 then w2
    float* st1 = ws + 8388608 + 2359296;
    float* st2 = st1 + 256;

    hipMemsetAsync(st1, 0, 512 * sizeof(float), stream);

    dim3 cgrid(8, 8, 16);

    // w1 = z@h1_w + h1_b ; conv1(x, w1) -> y1 (+stats1)
    hyper_gemm<<<WPB / 256, 256, 0, stream>>>(z, h1w, h1b, wsl);
    conv3x3<false><<<cgrid, 256, 0, stream>>>(x, wsl, y1, st1, nullptr, nullptr, nullptr);

    // w2 = z@h2_w + h2_b ; conv2(relu(gn1(y1)), w2) -> d_out raw (+stats2)
    hyper_gemm<<<WPB / 256, 256, 0, stream>>>(z, h2w, h2b, wsl);
    conv3x3<true><<<cgrid, 256, 0, stream>>>(y1, wsl, out, st2, st1, g1, b1);

    // out = relu(gn2(out) + x)
    gn_add_relu<<<2048, 256, 0, stream>>>(out, x, st2, g2, b2);
}

// Round 2
// 458.267 us; speedup vs baseline: 1.9201x; 1.9201x over previous
//
#include <hip/hip_runtime.h>

#define BB 16
#define CC 128
#define HH 64
#define WW 64
#define NG 8
#define WPB 147456       // 128*128*9 weights per sample
#define PLANE 4096       // 64*64
#define GROUP_N 65536.f  // 16 ch * 4096 px

typedef __attribute__((ext_vector_type(8))) short short8;
typedef __attribute__((ext_vector_type(4))) float floatx4;
typedef __attribute__((ext_vector_type(4))) unsigned short ushortx4;

__device__ __forceinline__ unsigned short f2bf(float f) {
    unsigned u = __builtin_bit_cast(unsigned, f);
    return (unsigned short)((u + 0x7fffu + ((u >> 16) & 1u)) >> 16);
}
__device__ __forceinline__ float bf2f(unsigned short h) {
    unsigned u = ((unsigned)h) << 16;
    return __builtin_bit_cast(float, u);
}

// ---------- transpose x (fp32 NCHW) -> Xt0[b][icc][y][x][ic32] bf16 ----------
__global__ __launch_bounds__(256)
void transpose_in(const float* __restrict__ x, unsigned short* __restrict__ xt)
{
    int blk = blockIdx.x;                 // 4096 = 16b * 4icc * 64y
    int b = blk >> 8, icc = (blk >> 6) & 3, y = blk & 63;
    int xi = threadIdx.x & 63, vg = threadIdx.x >> 6;   // vg 0..3 -> 8 channels
    const float* src = x + (((size_t)(b * CC + icc * 32 + vg * 8)) * HH + y) * WW + xi;
    short8 o;
#pragma unroll
    for (int e = 0; e < 8; ++e) o[e] = (short)f2bf(src[(size_t)e * PLANE]);
    unsigned short* dst = xt + (((size_t)(b * 4 + icc) * PLANE) + y * WW + xi) * 32 + vg * 8;
    *(short8*)dst = o;
}

// ---------- hypernet GEMM + pack to MFMA A-fragment layout -------------------
// Wf[b][icc][tap][frag][lane][j] bf16 where
//   oc = frag*16 + (lane&15), ic = icc*32 + (lane>>4)*8 + j
__global__ __launch_bounds__(256)
void hyper_gemm(const float* __restrict__ z, const float* __restrict__ hw,
                const float* __restrict__ hb, unsigned short* __restrict__ wf)
{
    __shared__ float zs[BB * 128];
    __shared__ unsigned short wlds[BB][576];
    const int tid = threadIdx.x;
    for (int i = tid; i < BB * 128; i += 256) zs[i] = z[i];
    __syncthreads();

    const int oc = blockIdx.x >> 1, half = blockIdx.x & 1;
    const int base_n = oc * 1152 + half * 576;

    for (int c = 0; c < 3; ++c) {
        int nl = c * 256 + tid;
        if (nl < 576) {
            int n = base_n + nl;
            float acc[BB];
#pragma unroll
            for (int b = 0; b < BB; ++b) acc[b] = 0.f;
#pragma unroll 4
            for (int k = 0; k < 128; ++k) {
                float hv = hw[(size_t)k * WPB + n];
#pragma unroll
                for (int b = 0; b < BB; ++b) acc[b] += zs[b * 128 + k] * hv;
            }
            float bias = hb[n];
#pragma unroll
            for (int b = 0; b < BB; ++b) wlds[b][nl] = f2bf(acc[b] + bias);
        }
    }
    __syncthreads();

    const int frag = oc >> 4, lane_lo = oc & 15;
    for (int i = tid; i < 1152; i += 256) {        // 16b * 2icl * 9tap * 4hi
        int b = i / 72, r = i % 72;
        int icl = r / 36, r2 = r % 36;
        int tap = r2 >> 2, hi = r2 & 3;
        int icc = half * 2 + icl;
        short8 o;
#pragma unroll
        for (int j = 0; j < 8; ++j)
            o[j] = (short)wlds[b][(icl * 32 + hi * 8 + j) * 9 + tap];
        size_t off = ((((size_t)(b * 4 + icc) * 9 + tap) * 8 + frag) * 64 + (lane_lo | (hi << 4))) * 8;
        *(short8*)(wf + off) = o;
    }
}

// ---------- MFMA conv: 9 tap-shifted GEMMs over ic-chunks --------------------
// block = 4 waves: wave(i=m-half, j=row). Block tile: 128 oc x 2 rows x 64 px.
// MODE 0: write bf16 Xt layout + stats ; MODE 1: write fp32 NCHW + stats
template <int MODE>
__global__ __launch_bounds__(256, 2)
void conv_mfma(const unsigned short* __restrict__ xt,
               const unsigned short* __restrict__ wf,
               unsigned short* __restrict__ yt, float* __restrict__ ynchw,
               float* __restrict__ stats)
{
    const int blk = blockIdx.x;          // 512 = 16b * 32tiles
    const int b = blk >> 5, tile = blk & 31;
    const int tid = threadIdx.x;
    const int w = tid >> 6, lane = tid & 63;
    const int i = w >> 1, j = w & 1;     // m-half, row-within-tile
    const int q = lane >> 4, n16 = lane & 15;
    const int y = tile * 2 + j;

    floatx4 acc[4][4];
#pragma unroll
    for (int mf = 0; mf < 4; ++mf)
#pragma unroll
        for (int nf = 0; nf < 4; ++nf) acc[mf][nf] = (floatx4)0.f;

    const unsigned short* xtb_b = xt + (size_t)b * 4 * PLANE * 32;
    const unsigned short* wf_b  = wf + (size_t)b * WPB;

    for (int icc = 0; icc < 4; ++icc) {
        const unsigned short* xtb = xtb_b + (size_t)icc * PLANE * 32;
        const unsigned short* wfc = wf_b + (size_t)icc * 36864;   // 9*8*64*8
#pragma unroll
        for (int tap = 0; tap < 9; ++tap) {
            const int dy = tap / 3 - 1, dx = tap % 3 - 1;
            const int yy = y + dy;
            if ((unsigned)yy >= (unsigned)HH) continue;   // wave-uniform

            short8 a[4], bbf[4];
#pragma unroll
            for (int mf = 0; mf < 4; ++mf)
                a[mf] = *(const short8*)(wfc + (((size_t)(tap * 8 + i * 4 + mf)) * 64 + lane) * 8);
#pragma unroll
            for (int nf = 0; nf < 4; ++nf) {
                int xx = nf * 16 + n16 + dx;
                if ((unsigned)xx < (unsigned)WW)
                    bbf[nf] = *(const short8*)(xtb + ((size_t)(yy * WW + xx)) * 32 + q * 8);
                else
                    bbf[nf] = (short8)0;
            }
#pragma unroll
            for (int mf = 0; mf < 4; ++mf)
#pragma unroll
                for (int nf = 0; nf < 4; ++nf)
                    acc[mf][nf] = __builtin_amdgcn_mfma_f32_16x16x32_bf16(
                        a[mf], bbf[nf], acc[mf][nf], 0, 0, 0);
        }
    }

    // ---- epilogue: store + fused GN stats (group g == i*4 + mf) ----
#pragma unroll
    for (int mf = 0; mf < 4; ++mf) {
        float s1 = 0.f, s2 = 0.f;
#pragma unroll
        for (int nf = 0; nf < 4; ++nf) {
#pragma unroll
            for (int r = 0; r < 4; ++r) {
                float v = acc[mf][nf][r];
                s1 += v; s2 += v * v;
            }
            const int xx = nf * 16 + n16;
            if (MODE == 0) {
                const int icc1 = i * 2 + (mf >> 1);
                const int v0 = (mf & 1) * 16 + q * 4;
                unsigned short* p = yt + (((size_t)(b * 4 + icc1) * PLANE) + y * WW + xx) * 32 + v0;
                ushortx4 u;
                u.x = f2bf(acc[mf][nf][0]); u.y = f2bf(acc[mf][nf][1]);
                u.z = f2bf(acc[mf][nf][2]); u.w = f2bf(acc[mf][nf][3]);
                *(ushortx4*)p = u;
            } else {
#pragma unroll
                for (int r = 0; r < 4; ++r) {
                    int oc = i * 64 + mf * 16 + q * 4 + r;
                    ynchw[(((size_t)(b * CC + oc)) * HH + y) * WW + xx] = acc[mf][nf][r];
                }
            }
        }
#pragma unroll
        for (int off = 32; off > 0; off >>= 1) {
            s1 += __shfl_down(s1, off, 64);
            s2 += __shfl_down(s2, off, 64);
        }
        if (lane == 0) {
            int g = i * 4 + mf;
            atomicAdd(&stats[(b * NG + g) * 2 + 0], s1);
            atomicAdd(&stats[(b * NG + g) * 2 + 1], s2);
        }
    }
}

// ---------- in-place GN1 + ReLU over bf16 Xt layout --------------------------
__global__ __launch_bounds__(256)
void norm_relu_bf16(unsigned short* __restrict__ yt, const float* __restrict__ stats,
                    const float* __restrict__ gamma, const float* __restrict__ beta)
{
    int idx8 = blockIdx.x * 256 + threadIdx.x;      // 1,048,576 groups of 8
    int t = idx8 >> 2;
    int bicc = t >> 12;
    int b = bicc >> 2, icc = bicc & 3;
    int cb = icc * 32 + (idx8 & 3) * 8;             // 8 consecutive channels, one group
    int g = cb >> 4;
    float sum = stats[(b * NG + g) * 2 + 0];
    float ssq = stats[(b * NG + g) * 2 + 1];
    float mean = sum * (1.f / GROUP_N);
    float var  = ssq * (1.f / GROUP_N) - mean * mean;
    float inv  = rsqrtf(var + 1e-5f);

    short8 d = *(short8*)(yt + (size_t)idx8 * 8);
    short8 o;
#pragma unroll
    for (int e = 0; e < 8; ++e) {
        float s = gamma[cb + e] * inv;
        float tt = beta[cb + e] - mean * s;
        float v = bf2f((unsigned short)d[e]);
        o[e] = (short)f2bf(fmaxf(v * s + tt, 0.f));
    }
    *(short8*)(yt + (size_t)idx8 * 8) = o;
}

// ---------- final: out = relu(GN2(y2) + x), in place over d_out --------------
__global__ __launch_bounds__(256)
void gn_add_relu(float* __restrict__ y2, const float* __restrict__ x,
                 const float* __restrict__ stats, const float* __restrict__ gamma,
                 const float* __restrict__ beta)
{
    const int bc = blockIdx.x;
    const int b = bc >> 7, c = bc & 127;
    const int g = c >> 4;
    float sum  = stats[(b * NG + g) * 2 + 0];
    float ssq  = stats[(b * NG + g) * 2 + 1];
    float mean = sum * (1.f / GROUP_N);
    float var  = ssq * (1.f / GROUP_N) - mean * mean;
    float inv  = rsqrtf(var + 1e-5f);
    float s = gamma[c] * inv;
    float t = beta[c] - mean * s;

    size_t base = (size_t)bc * PLANE;
    float4* yp = (float4*)(y2 + base);
    const float4* xp = (const float4*)(x + base);
    for (int i = threadIdx.x; i < PLANE / 4; i += 256) {
        float4 v = yp[i], xv = xp[i];
        v.x = fmaxf(v.x * s + t + xv.x, 0.f);
        v.y = fmaxf(v.y * s + t + xv.y, 0.f);
        v.z = fmaxf(v.z * s + t + xv.z, 0.f);
        v.w = fmaxf(v.w * s + t + xv.w, 0.f);
        yp[i] = v;
    }
}

extern "C" void kernel_launch(void* const* d_in, const int* in_sizes, int n_in,
                              void* d_out, int out_size, void* d_ws, size_t ws_size,
                              hipStream_t stream)
{
    const float* x   = (const float*)d_in[0];
    const float* z   = (const float*)d_in[1];
    const float* h1w = (const float*)d_in[2];
    const float* h1b = (const float*)d_in[3];
    const float* h2w = (const float*)d_in[4];
    const float* h2b = (const float*)d_in[5];
    const float* g1  = (const float*)d_in[6];
    const float* b1  = (const float*)d_in[7];
    const float* g2  = (const float*)d_in[8];
    const float* b2  = (const float*)d_in[9];
    float* out = (float*)d_out;

    // ws layout: stats1(256f) | stats2(256f) | Wf bf16 (4,718,592B) | Xt0 | Xt1
    float* stats1 = (float*)d_ws;
    float* stats2 = stats1 + 256;
    unsigned short* wfb = (unsigned short*)((char*)d_ws + 2048);
    unsigned short* xt0 = (unsigned short*)((char*)d_ws + 2048 + 4718592);
    unsigned short* xt1 = xt0 + 8388608;

    hipMemsetAsync(d_ws, 0, 2048, stream);

    // x -> Xt0 (bf16, ic-contiguous chunks)
    transpose_in<<<4096, 256, 0, stream>>>(x, xt0);

    // w1 -> fragment layout ; conv1 -> Xt1 raw + stats1
    hyper_gemm<<<256, 256, 0, stream>>>(z, h1w, h1b, wfb);
    conv_mfma<0><<<512, 256, 0, stream>>>(xt0, wfb, xt1, nullptr, stats1);

    // GN1 + ReLU in place on Xt1
    norm_relu_bf16<<<4096, 256, 0, stream>>>(xt1, stats1, g1, b1);

    // w2 -> fragment layout ; conv2 -> d_out raw fp32 + stats2
    hyper_gemm<<<256, 256, 0, stream>>>(z, h2w, h2b, wfb);
    conv_mfma<1><<<512, 256, 0, stream>>>(xt1, wfb, nullptr, out, stats2);

    // out = relu(GN2(out) + x)
    gn_add_relu<<<2048, 256, 0, stream>>>(out, x, stats2, g2, b2);
}

// Round 3
// 373.914 us; speedup vs baseline: 2.3533x; 1.2256x over previous
//
#include <hip/hip_runtime.h>

#define BB 16
#define CC 128
#define HH 64
#define WW 64
#define NG 8
#define WPB 147456       // 128*128*9 weights per sample
#define PLANE 4096       // 64*64
#define GROUP_N 65536.f  // 16 ch * 4096 px

typedef __attribute__((ext_vector_type(8))) short short8;
typedef __attribute__((ext_vector_type(4))) float floatx4;
typedef __attribute__((ext_vector_type(4))) unsigned short ushortx4;

__device__ __forceinline__ unsigned short f2bf(float f) {
    unsigned u = __builtin_bit_cast(unsigned, f);
    return (unsigned short)((u + 0x7fffu + ((u >> 16) & 1u)) >> 16);
}
__device__ __forceinline__ float bf2f(unsigned short h) {
    unsigned u = ((unsigned)h) << 16;
    return __builtin_bit_cast(float, u);
}

// ---------- transpose x (fp32 NCHW) -> Xt0[b][icc][y][x][ic32] bf16 ----------
__global__ __launch_bounds__(256)
void transpose_in(const float* __restrict__ x, unsigned short* __restrict__ xt)
{
    int blk = blockIdx.x;                 // 4096 = 16b * 4icc * 64y
    int b = blk >> 8, icc = (blk >> 6) & 3, y = blk & 63;
    int xi = threadIdx.x & 63, vg = threadIdx.x >> 6;   // vg 0..3 -> 8 channels
    const float* src = x + (((size_t)(b * CC + icc * 32 + vg * 8)) * HH + y) * WW + xi;
    short8 o;
#pragma unroll
    for (int e = 0; e < 8; ++e) o[e] = (short)f2bf(src[(size_t)e * PLANE]);
    unsigned short* dst = xt + (((size_t)(b * 4 + icc) * PLANE) + y * WW + xi) * 32 + vg * 8;
    *(short8*)dst = o;
}

// ---------- streaming hypernet GEMM (both heads): P[which][b][n] bf16 --------
// grid 1152: blk<576 -> head1 n-chunk, else head2. 1 n-column per thread.
__global__ __launch_bounds__(256)
void stream_gemm(const float* __restrict__ z,
                 const float* __restrict__ h1w, const float* __restrict__ h1b,
                 const float* __restrict__ h2w, const float* __restrict__ h2b,
                 unsigned short* __restrict__ P)
{
    const int blk = blockIdx.x;
    const int which = (blk >= 576) ? 1 : 0;
    const int n = (blk - which * 576) * 256 + threadIdx.x;
    const float* __restrict__ hw = which ? h2w : h1w;
    const float* __restrict__ hb = which ? h2b : h1b;
    unsigned short* pw = P + (size_t)which * 2359296;

    float acc[BB];
#pragma unroll
    for (int b = 0; b < BB; ++b) acc[b] = 0.f;

    for (int k0 = 0; k0 < 128; k0 += 8) {
        float hv[8];
#pragma unroll
        for (int u = 0; u < 8; ++u) hv[u] = hw[(size_t)(k0 + u) * WPB + n];
#pragma unroll
        for (int u = 0; u < 8; ++u) {
#pragma unroll
            for (int b = 0; b < BB; ++b)
                acc[b] = fmaf(z[b * 128 + k0 + u], hv[u], acc[b]);  // z: uniform -> s_load
        }
    }
    const float bias = hb[n];
#pragma unroll
    for (int b = 0; b < BB; ++b)
        pw[(size_t)b * WPB + n] = f2bf(acc[b] + bias);
}

// ---------- repack plain P[b][n] -> MFMA A-fragment layout -------------------
// Wf[b][icc][tap][frag][lane][j], oc=frag*16+(lane&15), ic=icc*32+(lane>>4)*8+j
// Each thread: 72 contiguous ushorts in (9x short8 loads), 9 short8 stores.
__global__ __launch_bounds__(256)
void repack(const unsigned short* __restrict__ P,
            unsigned short* __restrict__ wf1, unsigned short* __restrict__ wf2)
{
    int gid = blockIdx.x * 256 + threadIdx.x;   // 65536 = 2 * 16b*4icc*8frag*64lane
    int which = gid >> 15, g = gid & 32767;
    int lane = g & 63, frag = (g >> 6) & 7, icc = (g >> 9) & 3, b = g >> 11;

    const unsigned short* src = P + (size_t)which * 2359296 + (size_t)b * WPB
        + (frag * 16 + (lane & 15)) * 1152 + (icc * 32 + (lane >> 4) * 8) * 9;
    unsigned short buf[72];
#pragma unroll
    for (int i = 0; i < 9; ++i)
        *(short8*)(buf + i * 8) = *(const short8*)(src + i * 8);  // 16B-aligned

    unsigned short* wf = which ? wf2 : wf1;
#pragma unroll
    for (int tap = 0; tap < 9; ++tap) {
        short8 o;
#pragma unroll
        for (int j = 0; j < 8; ++j) o[j] = (short)buf[j * 9 + tap];
        size_t off = ((((size_t)(b * 4 + icc) * 9 + tap) * 8 + frag) * 64 + lane) * 8;
        *(short8*)(wf + off) = o;   // contiguous 1KB per wave per tap
    }
}

// ---------- MFMA conv: 9 tap-shifted GEMMs over ic-chunks --------------------
// block = 4 waves: wave(i=m-half, j=row). Block tile: 128 oc x 2 rows x 64 px.
// MODE 0: write bf16 Xt layout + stats ; MODE 1: write fp32 NCHW + stats
template <int MODE>
__global__ __launch_bounds__(256, 2)
void conv_mfma(const unsigned short* __restrict__ xt,
               const unsigned short* __restrict__ wf,
               unsigned short* __restrict__ yt, float* __restrict__ ynchw,
               float* __restrict__ stats)
{
    const int blk = blockIdx.x;          // 512 = 16b * 32tiles
    const int b = blk >> 5, tile = blk & 31;
    const int tid = threadIdx.x;
    const int w = tid >> 6, lane = tid & 63;
    const int i = w >> 1, j = w & 1;     // m-half, row-within-tile
    const int q = lane >> 4, n16 = lane & 15;
    const int y = tile * 2 + j;

    floatx4 acc[4][4];
#pragma unroll
    for (int mf = 0; mf < 4; ++mf)
#pragma unroll
        for (int nf = 0; nf < 4; ++nf) acc[mf][nf] = (floatx4)0.f;

    const unsigned short* xtb_b = xt + (size_t)b * 4 * PLANE * 32;
    const unsigned short* wf_b  = wf + (size_t)b * WPB;

    for (int icc = 0; icc < 4; ++icc) {
        const unsigned short* xtb = xtb_b + (size_t)icc * PLANE * 32;
        const unsigned short* wfc = wf_b + (size_t)icc * 36864;   // 9*8*64*8
#pragma unroll
        for (int tap = 0; tap < 9; ++tap) {
            const int dy = tap / 3 - 1, dx = tap % 3 - 1;
            const int yy = y + dy;
            if ((unsigned)yy >= (unsigned)HH) continue;   // wave-uniform

            short8 a[4], bbf[4];
#pragma unroll
            for (int mf = 0; mf < 4; ++mf)
                a[mf] = *(const short8*)(wfc + (((size_t)(tap * 8 + i * 4 + mf)) * 64 + lane) * 8);
#pragma unroll
            for (int nf = 0; nf < 4; ++nf) {
                int xx = nf * 16 + n16 + dx;
                if ((unsigned)xx < (unsigned)WW)
                    bbf[nf] = *(const short8*)(xtb + ((size_t)(yy * WW + xx)) * 32 + q * 8);
                else
                    bbf[nf] = (short8)0;
            }
#pragma unroll
            for (int mf = 0; mf < 4; ++mf)
#pragma unroll
                for (int nf = 0; nf < 4; ++nf)
                    acc[mf][nf] = __builtin_amdgcn_mfma_f32_16x16x32_bf16(
                        a[mf], bbf[nf], acc[mf][nf], 0, 0, 0);
        }
    }

    // ---- epilogue: store + fused GN stats (group g == i*4 + mf) ----
#pragma unroll
    for (int mf = 0; mf < 4; ++mf) {
        float s1 = 0.f, s2 = 0.f;
#pragma unroll
        for (int nf = 0; nf < 4; ++nf) {
#pragma unroll
            for (int r = 0; r < 4; ++r) {
                float v = acc[mf][nf][r];
                s1 += v; s2 += v * v;
            }
            const int xx = nf * 16 + n16;
            if (MODE == 0) {
                const int icc1 = i * 2 + (mf >> 1);
                const int v0 = (mf & 1) * 16 + q * 4;
                unsigned short* p = yt + (((size_t)(b * 4 + icc1) * PLANE) + y * WW + xx) * 32 + v0;
                ushortx4 u;
                u.x = f2bf(acc[mf][nf][0]); u.y = f2bf(acc[mf][nf][1]);
                u.z = f2bf(acc[mf][nf][2]); u.w = f2bf(acc[mf][nf][3]);
                *(ushortx4*)p = u;
            } else {
#pragma unroll
                for (int r = 0; r < 4; ++r) {
                    int oc = i * 64 + mf * 16 + q * 4 + r;
                    ynchw[(((size_t)(b * CC + oc)) * HH + y) * WW + xx] = acc[mf][nf][r];
                }
            }
        }
#pragma unroll
        for (int off = 32; off > 0; off >>= 1) {
            s1 += __shfl_down(s1, off, 64);
            s2 += __shfl_down(s2, off, 64);
        }
        if (lane == 0) {
            int g = i * 4 + mf;
            atomicAdd(&stats[(b * NG + g) * 2 + 0], s1);
            atomicAdd(&stats[(b * NG + g) * 2 + 1], s2);
        }
    }
}

// ---------- in-place GN1 + ReLU over bf16 Xt layout --------------------------
__global__ __launch_bounds__(256)
void norm_relu_bf16(unsigned short* __restrict__ yt, const float* __restrict__ stats,
                    const float* __restrict__ gamma, const float* __restrict__ beta)
{
    int idx8 = blockIdx.x * 256 + threadIdx.x;      // 1,048,576 groups of 8
    int t = idx8 >> 2;
    int bicc = t >> 12;
    int b = bicc >> 2, icc = bicc & 3;
    int cb = icc * 32 + (idx8 & 3) * 8;             // 8 consecutive channels, one group
    int g = cb >> 4;
    float sum = stats[(b * NG + g) * 2 + 0];
    float ssq = stats[(b * NG + g) * 2 + 1];
    float mean = sum * (1.f / GROUP_N);
    float var  = ssq * (1.f / GROUP_N) - mean * mean;
    float inv  = rsqrtf(var + 1e-5f);

    short8 d = *(short8*)(yt + (size_t)idx8 * 8);
    short8 o;
#pragma unroll
    for (int e = 0; e < 8; ++e) {
        float s = gamma[cb + e] * inv;
        float tt = beta[cb + e] - mean * s;
        float v = bf2f((unsigned short)d[e]);
        o[e] = (short)f2bf(fmaxf(v * s + tt, 0.f));
    }
    *(short8*)(yt + (size_t)idx8 * 8) = o;
}

// ---------- final: out = relu(GN2(y2) + x), in place over d_out --------------
__global__ __launch_bounds__(256)
void gn_add_relu(float* __restrict__ y2, const float* __restrict__ x,
                 const float* __restrict__ stats, const float* __restrict__ gamma,
                 const float* __restrict__ beta)
{
    const int bc = blockIdx.x;
    const int b = bc >> 7, c = bc & 127;
    const int g = c >> 4;
    float sum  = stats[(b * NG + g) * 2 + 0];
    float ssq  = stats[(b * NG + g) * 2 + 1];
    float mean = sum * (1.f / GROUP_N);
    float var  = ssq * (1.f / GROUP_N) - mean * mean;
    float inv  = rsqrtf(var + 1e-5f);
    float s = gamma[c] * inv;
    float t = beta[c] - mean * s;

    size_t base = (size_t)bc * PLANE;
    float4* yp = (float4*)(y2 + base);
    const float4* xp = (const float4*)(x + base);
    for (int i = threadIdx.x; i < PLANE / 4; i += 256) {
        float4 v = yp[i], xv = xp[i];
        v.x = fmaxf(v.x * s + t + xv.x, 0.f);
        v.y = fmaxf(v.y * s + t + xv.y, 0.f);
        v.z = fmaxf(v.z * s + t + xv.z, 0.f);
        v.w = fmaxf(v.w * s + t + xv.w, 0.f);
        yp[i] = v;
    }
}

extern "C" void kernel_launch(void* const* d_in, const int* in_sizes, int n_in,
                              void* d_out, int out_size, void* d_ws, size_t ws_size,
                              hipStream_t stream)
{
    const float* x   = (const float*)d_in[0];
    const float* z   = (const float*)d_in[1];
    const float* h1w = (const float*)d_in[2];
    const float* h1b = (const float*)d_in[3];
    const float* h2w = (const float*)d_in[4];
    const float* h2b = (const float*)d_in[5];
    const float* g1  = (const float*)d_in[6];
    const float* b1  = (const float*)d_in[7];
    const float* g2  = (const float*)d_in[8];
    const float* b2  = (const float*)d_in[9];
    float* out = (float*)d_out;

    // ws: stats(2048B) | Wf1(4.71MB) | Wf2(4.71MB) | Xt0(16.8MB) | Xt1(16.8MB)
    // P (plain bf16 GEMM out, 9.4MB) aliases Xt1 — lifetime ends at repack,
    // before conv1 overwrites Xt1.
    float* stats1 = (float*)d_ws;
    float* stats2 = stats1 + 256;
    unsigned short* wf1 = (unsigned short*)((char*)d_ws + 2048);
    unsigned short* wf2 = wf1 + 2359296;
    unsigned short* xt0 = wf2 + 2359296;
    unsigned short* xt1 = xt0 + 8388608;
    unsigned short* P   = xt1;   // alias

    hipMemsetAsync(d_ws, 0, 2048, stream);

    // x -> Xt0 (bf16, ic-contiguous chunks)
    transpose_in<<<4096, 256, 0, stream>>>(x, xt0);

    // both hypernet heads: stream 151MB once -> plain P, then repack to frags
    stream_gemm<<<1152, 256, 0, stream>>>(z, h1w, h1b, h2w, h2b, P);
    repack<<<256, 256, 0, stream>>>(P, wf1, wf2);

    // conv1 -> Xt1 raw + stats1 (overwrites P after repack is done)
    conv_mfma<0><<<512, 256, 0, stream>>>(xt0, wf1, xt1, nullptr, stats1);

    // GN1 + ReLU in place on Xt1
    norm_relu_bf16<<<4096, 256, 0, stream>>>(xt1, stats1, g1, b1);

    // conv2 -> d_out raw fp32 + stats2
    conv_mfma<1><<<512, 256, 0, stream>>>(xt1, wf2, nullptr, out, stats2);

    // out = relu(GN2(out) + x)
    gn_add_relu<<<2048, 256, 0, stream>>>(out, x, stats2, g2, b2);
}